// Round 14
// baseline (145.484 us; speedup 1.0000x reference)
//
#include <hip/hip_runtime.h>

#define IMG_H 512
#define IMG_W 512
#define IMG_N (IMG_H * IMG_W)
#define NPLANES 48          // 16 batch * 3 channels
#define TILE 64             // 64x64 output tile per "tile step"
#define NTILES 3072         // 8 x 8 x 48
#define GRID 1280           // 5 blocks/CU x 256 CUs — exactly resident
#define XS 88               // LDS row stride (elements); rows 16B-aligned
#define SSIM_C1 0.0001f
#define SSIM_C2 0.0009f

typedef _Float16 f16x2 __attribute__((ext_vector_type(2)));
typedef _Float16 f16x4 __attribute__((ext_vector_type(4)));
typedef _Float16 f16x8 __attribute__((ext_vector_type(8)));
typedef float    f32x4 __attribute__((ext_vector_type(4)));

__device__ __forceinline__ unsigned pk2(float a, float b) {   // 1 op: v_cvt_pkrtz
    return __builtin_bit_cast(unsigned,
        __builtin_amdgcn_cvt_pkrtz(a, b));                    // a -> low half
}
__device__ __forceinline__ f16x2 pk2h(float a, float b) {
    return __builtin_bit_cast(f16x2, __builtin_amdgcn_cvt_pkrtz(a, b));
}

// R13 structure (f16 MFMA conv, in-register H->V handoff, no lgkm ops in the
// channel loop) + R14: PERSISTENT BLOCKS. 1280 blocks (exactly 5/CU resident)
// each process tiles bid, bid+1280, bid+2560 — kills the 2.4-round dispatch
// tail that capped OccupancyPercent at ~40%.
__global__ __launch_bounds__(256) void ssim_mfma_kernel(
    const float* __restrict__ pred, const float* __restrict__ target,
    const float* __restrict__ window, float* __restrict__ partial)
{
    __shared__ unsigned short Xp[80 * XS];   // 14080 B
    __shared__ unsigned short Xt[80 * XS];   // 14080 B
    __shared__ unsigned short gfS[16];       // f16 taps, [11..15] = 0
    __shared__ float wsum[4];

    const int tid  = threadIdx.x;
    const int w    = tid >> 6;       // wave = col-tile (16 cols)
    const int lane = tid & 63;
    const int n15  = lane & 15;
    const int quad = lane >> 4;

    // f16 tap table: g[i] = row sums of the normalized 2D window (RNE cast)
    if (tid < 16) {
        float gv = 0.f;
        if (tid < 11) {
            float s = 0.f;
            #pragma unroll
            for (int j = 0; j < 11; ++j) s += window[tid * 11 + j];
            gv = s;
        }
        const _Float16 hg = (_Float16)gv;
        gfS[tid] = __builtin_bit_cast(unsigned short, hg);
    }
    __syncthreads();

    // ---- H weight fragment (B-op of 16x16x32): elem j -> g[8q+j - n15 - 3]
    uint4 wu;
    {
        unsigned wd[4];
        #pragma unroll
        for (int d = 0; d < 4; ++d) {
            const int t0 = 8 * quad + 2 * d - n15 - 3;
            const unsigned lo = gfS[((unsigned)t0       <= 10u) ? t0       : 11];
            const unsigned hi = gfS[((unsigned)(t0 + 1) <= 10u) ? (t0 + 1) : 11];
            wd[d] = lo | (hi << 16);
        }
        wu = make_uint4(wd[0], wd[1], wd[2], wd[3]);
    }
    const f16x8 wfrag = __builtin_bit_cast(f16x8, wu);

    // ---- V weight fragments (A-op of 16x16x16, k = 4q+j, m = n15):
    // w0[j] = g[k - m - 3]  (H tile rt),  w1[j] = g[k - m + 13]  (tile rt+1)
    f16x4 w0frag, w1frag;
    {
        unsigned a[2], b[2];
        #pragma unroll
        for (int d = 0; d < 2; ++d) {
            const int k0 = 4 * quad + 2 * d;
            const int a0 = k0 - n15 - 3,  a1 = a0 + 1;
            const int b0 = k0 - n15 + 13, b1 = b0 + 1;
            a[d] = gfS[((unsigned)a0 <= 10u) ? a0 : 11] |
                   ((unsigned)gfS[((unsigned)a1 <= 10u) ? a1 : 11] << 16);
            b[d] = gfS[((unsigned)b0 <= 10u) ? b0 : 11] |
                   ((unsigned)gfS[((unsigned)b1 <= 10u) ? b1 : 11] << 16);
        }
        w0frag = __builtin_bit_cast(f16x4, make_uint2(a[0], a[1]));
        w1frag = __builtin_bit_cast(f16x4, make_uint2(b[0], b[1]));
    }
    const f32x4 zero4 = {0.f, 0.f, 0.f, 0.f};

    float acc = 0.f;

    #pragma unroll 1
    for (int tile = blockIdx.x; tile < NTILES; tile += GRID) {
        const int plane  = tile >> 6;
        const int rem    = tile & 63;
        const int base_r = (rem >> 3) * TILE;
        const int base_c = (rem & 7) * TILE;
        const float* pp = pred   + (size_t)plane * IMG_N;
        const float* tp = target + (size_t)plane * IMG_N;

        __syncthreads();   // WAR: previous tile's X reads complete

        // ---- Stage p,t as f16: rows/cols [base-8, base+71], zero outside --
        #pragma unroll
        for (int i = 0; i < 7; ++i) {
            const unsigned fi = (unsigned)tid + 256u * i;  // 80 rows x 20 f4
            if (fi < 1600u) {
                const unsigned ri = fi / 20u, q = fi - 20u * ri;
                const int gr = base_r - 8 + (int)ri;
                const int gc = base_c - 8 + 4 * (int)q;
                const bool ok = ((unsigned)gr < (unsigned)IMG_H) &&
                                ((unsigned)gc < (unsigned)IMG_W);
                const float4 z4 = make_float4(0.f, 0.f, 0.f, 0.f);
                float4 p4 = ok ? *(const float4*)(pp + gr * IMG_W + gc) : z4;
                float4 t4 = ok ? *(const float4*)(tp + gr * IMG_W + gc) : z4;
                const int off = (int)ri * XS + 4 * (int)q;   // 8B-aligned
                *(uint2*)&Xp[off] = make_uint2(pk2(p4.x, p4.y), pk2(p4.z, p4.w));
                *(uint2*)&Xt[off] = make_uint2(pk2(t4.x, t4.y), pk2(t4.z, t4.w));
            }
        }
        __syncthreads();

        // H-pass for one 16-row tile h: 2 b128 X reads, 5 channels ->
        // P[ch] = C-layout result packed to f16x4 (rows 4q+0..3, col n15).
        auto h_tile = [&](int h, f16x4 (&P)[5]) {
            const int xoff = (16 * h + n15) * XS + 16 * w + 8 * quad; // 16B-al
            const f16x8 pu = *(const f16x8*)&Xp[xoff];
            const f16x8 tu = *(const f16x8*)&Xt[xoff];
            #pragma unroll
            for (int ch = 0; ch < 5; ++ch) {
                f16x8 au;
                if      (ch == 0) au = pu;
                else if (ch == 1) au = tu;
                else if (ch == 2) au = pu * pu;      // v_pk_mul_f16 x4
                else if (ch == 3) au = tu * tu;
                else              au = pu * tu;
                const f32x4 hd = __builtin_amdgcn_mfma_f32_16x16x32_f16(
                    au, wfrag, zero4, 0, 0, 0);
                const f16x2 l  = pk2h(hd[0], hd[1]);
                const f16x2 hh = pk2h(hd[2], hd[3]);
                P[ch] = f16x4{l.x, l.y, hh.x, hh.y};
            }
        };

        f16x4 Pprev[5], Pcur[5];
        h_tile(0, Pprev);

        #pragma unroll
        for (int rt = 0; rt < 4; ++rt) {
            h_tile(rt + 1, Pcur);
            f32x4 s[5];
            #pragma unroll
            for (int ch = 0; ch < 5; ++ch) {
                const f32x4 t = __builtin_amdgcn_mfma_f32_16x16x16f16(
                    w0frag, Pprev[ch], zero4, 0, 0, 0);
                s[ch] = __builtin_amdgcn_mfma_f32_16x16x16f16(
                    w1frag, Pcur[ch], t, 0, 0, 0);
            }
            // SSIM for the 4 pixels this lane owns in tile rt
            #pragma unroll
            for (int r = 0; r < 4; ++r) {
                const float mu1 = s[0][r], mu2 = s[1][r];
                const float e11 = s[2][r], e22 = s[3][r], e12 = s[4][r];
                const float mu1_sq = mu1 * mu1, mu2_sq = mu2 * mu2;
                const float mu1_mu2 = mu1 * mu2;
                const float s1  = e11 - mu1_sq;
                const float s2  = e22 - mu2_sq;
                const float s12 = e12 - mu1_mu2;
                const float num = (2.f * mu1_mu2 + SSIM_C1) * (2.f * s12 + SSIM_C2);
                const float den = (mu1_sq + mu2_sq + SSIM_C1) * (s1 + s2 + SSIM_C2);
                acc += num * __builtin_amdgcn_rcpf(den);
            }
            #pragma unroll
            for (int ch = 0; ch < 5; ++ch) Pprev[ch] = Pcur[ch];
        }
    }

    // ---- Block reduction (once, after all tiles) ----
    #pragma unroll
    for (int off = 32; off > 0; off >>= 1)
        acc += __shfl_down(acc, off, 64);
    __syncthreads();                 // reuse wsum safely
    if (lane == 0) wsum[w] = acc;
    __syncthreads();
    if (tid == 0)
        partial[blockIdx.x] = wsum[0] + wsum[1] + wsum[2] + wsum[3];
}

// Reduce 1280 partials -> scalar (double accumulate)
__global__ __launch_bounds__(256) void ssim_reduce_kernel(
    const float* __restrict__ partial, float* __restrict__ out)
{
    const int tid = threadIdx.x;
    float s = 0.f;
    #pragma unroll
    for (int k = 0; k < 5; ++k) s += partial[tid + 256 * k];
    double acc = (double)s;
    #pragma unroll
    for (int off = 32; off > 0; off >>= 1)
        acc += __shfl_down(acc, off, 64);
    __shared__ double wsumd[4];
    const int lane = tid & 63, wid = tid >> 6;
    if (lane == 0) wsumd[wid] = acc;
    __syncthreads();
    if (tid == 0) {
        const double total = wsumd[0] + wsumd[1] + wsumd[2] + wsumd[3];
        const double N = (double)NPLANES * IMG_H * IMG_W;
        out[0] = (float)(1.0 - total / N);
    }
}

extern "C" void kernel_launch(void* const* d_in, const int* in_sizes, int n_in,
                              void* d_out, int out_size, void* d_ws, size_t ws_size,
                              hipStream_t stream)
{
    const float* pred   = (const float*)d_in[0];
    const float* target = (const float*)d_in[1];
    const float* window = (const float*)d_in[2];
    float* out = (float*)d_out;
    float* partial = (float*)d_ws;   // 1280 floats = 5 KiB

    ssim_mfma_kernel<<<GRID, 256, 0, stream>>>(pred, target, window, partial);
    ssim_reduce_kernel<<<1, 256, 0, stream>>>(partial, out);
}